// Round 3
// baseline (204.928 us; speedup 1.0000x reference)
//
#include <hip/hip_runtime.h>

// OverlapPatchEmbed: x (64,3,224,224) fp32 -> out (64,729,3,256) fp32.
// patch=16, stride=8, n=27 patches/dim.
//
// R8: INSTRUMENTATION ROUND. Kernel body is exactly R5 (best known,
// 173.1 us iteration). The only change: kernel_launch enqueues the
// SAME kernel TWICE back-to-back (idempotent -> identical output,
// graph-capture-safe). Purpose: dur_us(R8) - dur_us(R7) ~= one kernel
// duration K, which the top-5 counter table cannot reveal (it is fully
// occupied by ~130 fillBufferAligned dispatches at 83-87 us).
//
// Decision rule (pre-committed):
//   dur ~200-215 -> K~35 us -> kernel already at the ~218MB/6.3TB/s
//                   mixed roofline; residual iteration time is harness
//                   resets -> restore single launch, declare roofline.
//   dur ~240-260 -> K~75 us -> ~2x headroom; pursue persistent
//                   double-buffered structure with global_load_lds +
//                   counted vmcnt.
//
// Block = (b, py) covering ALL 3 channels. Stage the 3x16x224 band
// (43.7 KB LDS, row stride 228 floats) with coalesced loads, then emit
// the 27 patches x 3 ch x 1 KB = 81 KB output region PERFECTLY
// SEQUENTIALLY (out float4 index == loop index).
// Occupancy: 512 thr, 43.7 KB LDS -> 3 blocks/CU = 24 waves/CU.

typedef float nfloat4 __attribute__((ext_vector_type(4)));

constexpr int NB  = 64;
constexpr int NC  = 3;
constexpr int HWD = 224;
constexpr int PS  = 16;    // patch size
constexpr int ST  = 8;     // stride
constexpr int NP  = 27;    // patches per dim
constexpr int ROW4 = HWD / 4;          // 56 float4 per image row
constexpr int LDSW = 228;              // LDS row stride in floats (+4 pad)
constexpr int TPB  = 512;
constexpr int NLOAD4  = NC * PS * ROW4;      // 2688 float4 staged per block
constexpr int NSTORE4 = NP * NC * 64;        // 5184 float4 written per block

__global__ __launch_bounds__(TPB) void overlap_patch_seq(
    const nfloat4* __restrict__ x, nfloat4* __restrict__ out)
{
    const int py = blockIdx.x % NP;
    const int b  = blockIdx.x / NP;

    __shared__ float lds[NC * PS * LDSW];   // 43776 B

    const int t = threadIdx.x;

    // Stage 1: load 3 channel-bands of 16 rows x 56 float4, coalesced.
    #pragma unroll
    for (int k = 0; k < 6; ++k) {
        const int j = t + k * TPB;
        if (j < NLOAD4) {
            const int c    = j / (PS * ROW4);        // 0..2
            const int rem  = j - c * (PS * ROW4);
            const int r    = rem / ROW4;             // 0..15
            const int col4 = rem - r * ROW4;         // 0..55
            const nfloat4 v = x[((b * NC + c) * HWD + py * ST + r) * ROW4 + col4];
            *(nfloat4*)&lds[(c * PS + r) * LDSW + col4 * 4] = v;
        }
    }
    __syncthreads();

    // Stage 2: write 81 KB sequentially. Output float4 index j maps to
    // px = j/192, c = (j%192)/64, q4 = j%64; r = q4>>2, s = (q4&3)*4.
    const long obase = (long)(b * NP * NP + py * NP) * (NC * 64);  // float4
    #pragma unroll
    for (int k = 0; k < 11; ++k) {
        const int j = t + k * TPB;
        if (j < NSTORE4) {
            const int px  = j / (NC * 64);
            const int rem = j - px * (NC * 64);
            const int c   = rem >> 6;
            const int q4  = rem & 63;
            const int r   = q4 >> 2;
            const int s   = (q4 & 3) << 2;
            const nfloat4 v = *(const nfloat4*)&lds[(c * PS + r) * LDSW + px * ST + s];
            out[obase + j] = v;
        }
    }
}

extern "C" void kernel_launch(void* const* d_in, const int* in_sizes, int n_in,
                              void* d_out, int out_size, void* d_ws, size_t ws_size,
                              hipStream_t stream) {
    const nfloat4* x = (const nfloat4*)d_in[0];
    nfloat4* out = (nfloat4*)d_out;
    const int grid = NB * NP;   // 1728 blocks
    // Double launch: idempotent. Second launch's duration == one kernel
    // time K, exposing K via dur_us delta vs the single-launch R7 bench.
    overlap_patch_seq<<<grid, TPB, 0, stream>>>(x, out);
    overlap_patch_seq<<<grid, TPB, 0, stream>>>(x, out);
}

// Round 4
// 173.407 us; speedup vs baseline: 1.1818x; 1.1818x over previous
//
#include <hip/hip_runtime.h>

// OverlapPatchEmbed: x (64,3,224,224) fp32 -> out (64,729,3,256) fp32.
// patch=16, stride=8, n=27 patches/dim.
//
// R9 = R5 restored (best known: 173.1 us iteration). FINAL.
//
// R8's double-launch instrumentation measured the kernel's standalone
// duration: dur_us 175.5 -> 204.9 => K ~= 29-32 us. Roofline arithmetic:
// reads 38.5-74 MB (py-band overlap, partially L3-served) + writes
// 143.3 MB = 182-217 MB; at the 6.3 TB/s achievable HBM ceiling that is
// 29-34.5 us. The kernel is AT the mixed-stream memory roofline within a
// few percent. The remaining ~140 us of the iteration is harness fixture:
// one 573 MB poison fill (~85 us at 85% of peak -- the top-5 rows every
// round) + dozens of tiny reset dispatches + graph gaps. Not addressable
// from kernel source. R6 (no-LDS gather, +7.7us) and R7 (XCD swizzle,
// +2.4us) confirmed structural changes only perturb a ~30us component.
//
// Structure: block = (b, py) covering ALL 3 channels. Stage the 3x16x224
// band (43.7 KB LDS, row stride 228 floats) with coalesced loads, then
// emit the 27 patches x 3 ch x 1 KB = 81 KB output region PERFECTLY
// SEQUENTIALLY (out float4 index == loop index).
// Occupancy: 512 thr, 43.7 KB LDS -> 3 blocks/CU = 24 waves/CU.

typedef float nfloat4 __attribute__((ext_vector_type(4)));

constexpr int NB  = 64;
constexpr int NC  = 3;
constexpr int HWD = 224;
constexpr int PS  = 16;    // patch size
constexpr int ST  = 8;     // stride
constexpr int NP  = 27;    // patches per dim
constexpr int ROW4 = HWD / 4;          // 56 float4 per image row
constexpr int LDSW = 228;              // LDS row stride in floats (+4 pad)
constexpr int TPB  = 512;
constexpr int NLOAD4  = NC * PS * ROW4;      // 2688 float4 staged per block
constexpr int NSTORE4 = NP * NC * 64;        // 5184 float4 written per block

__global__ __launch_bounds__(TPB) void overlap_patch_seq(
    const nfloat4* __restrict__ x, nfloat4* __restrict__ out)
{
    const int py = blockIdx.x % NP;
    const int b  = blockIdx.x / NP;

    __shared__ float lds[NC * PS * LDSW];   // 43776 B

    const int t = threadIdx.x;

    // Stage 1: load 3 channel-bands of 16 rows x 56 float4, coalesced.
    #pragma unroll
    for (int k = 0; k < 6; ++k) {
        const int j = t + k * TPB;
        if (j < NLOAD4) {
            const int c    = j / (PS * ROW4);        // 0..2
            const int rem  = j - c * (PS * ROW4);
            const int r    = rem / ROW4;             // 0..15
            const int col4 = rem - r * ROW4;         // 0..55
            const nfloat4 v = x[((b * NC + c) * HWD + py * ST + r) * ROW4 + col4];
            *(nfloat4*)&lds[(c * PS + r) * LDSW + col4 * 4] = v;
        }
    }
    __syncthreads();

    // Stage 2: write 81 KB sequentially. Output float4 index j maps to
    // px = j/192, c = (j%192)/64, q4 = j%64; r = q4>>2, s = (q4&3)*4.
    const long obase = (long)(b * NP * NP + py * NP) * (NC * 64);  // float4
    #pragma unroll
    for (int k = 0; k < 11; ++k) {
        const int j = t + k * TPB;
        if (j < NSTORE4) {
            const int px  = j / (NC * 64);
            const int rem = j - px * (NC * 64);
            const int c   = rem >> 6;
            const int q4  = rem & 63;
            const int r   = q4 >> 2;
            const int s   = (q4 & 3) << 2;
            const nfloat4 v = *(const nfloat4*)&lds[(c * PS + r) * LDSW + px * ST + s];
            out[obase + j] = v;
        }
    }
}

extern "C" void kernel_launch(void* const* d_in, const int* in_sizes, int n_in,
                              void* d_out, int out_size, void* d_ws, size_t ws_size,
                              hipStream_t stream) {
    const nfloat4* x = (const nfloat4*)d_in[0];
    nfloat4* out = (nfloat4*)d_out;
    const int grid = NB * NP;   // 1728 blocks
    overlap_patch_seq<<<grid, TPB, 0, stream>>>(x, out);
}